// Round 1
// baseline (147.688 us; speedup 1.0000x reference)
//
#include <hip/hip_runtime.h>
#include <math.h>

// Problem: B=16, N=512, F=256.
// Live computation only (attention matrix is dead code in the reference):
//   h       = x @ W_w^T + W_b                      [B,N,F]
//   h_prime = leaky_relu(adj @ h, 0.2)             [B,N,F]
//   g       = [x, h_prime] @ gate_w^T + gate_b     [B,N,1]
//   out     = sigmoid(g)*x + (1-sigmoid(g))*h_prime

#define BATCH 16
#define NNODE 512
#define FDIM  256
#define M_TOT (BATCH * NNODE)   // 8192

// ---------------- Kernel 1: h = x @ W^T + bias ----------------
// [8192,256] x [256,256]^T. BM=BN=BK=64, 256 threads, 4x4 micro-tile.
#define BM 64
#define BN 64
#define BK 64
#define LDSS 68  // padded stride (floats) to break bank conflicts

__global__ __launch_bounds__(256) void h_gemm(const float* __restrict__ x,
                                              const float* __restrict__ W,
                                              const float* __restrict__ bias,
                                              float* __restrict__ h) {
    __shared__ float As[BM][LDSS];
    __shared__ float Bs[BN][LDSS];
    const int t  = threadIdx.x;
    const int tx = t & 15;        // n micro index
    const int ty = t >> 4;        // m micro index
    const int m0 = (int)(blockIdx.x >> 2) * BM;  // 128 m-tiles
    const int n0 = (int)(blockIdx.x & 3) * BN;   // 4 n-tiles

    float acc[4][4] = {};

    for (int k0 = 0; k0 < FDIM; k0 += BK) {
        // Cooperative load: 64x64 tile = 1024 float4; 4 float4 per thread.
#pragma unroll
        for (int i = 0; i < 4; i++) {
            int fid = t + i * 256;          // 0..1023
            int row = fid >> 4;             // 0..63
            int c4  = (fid & 15) << 2;      // 0..60
            float4 av = *(const float4*)(x + (size_t)(m0 + row) * FDIM + k0 + c4);
            *(float4*)&As[row][c4] = av;
            float4 bv = *(const float4*)(W + (size_t)(n0 + row) * FDIM + k0 + c4);
            *(float4*)&Bs[row][c4] = bv;
        }
        __syncthreads();

#pragma unroll
        for (int kk = 0; kk < BK; kk += 4) {
            float4 a4[4], b4[4];
#pragma unroll
            for (int i = 0; i < 4; i++) a4[i] = *(const float4*)&As[4 * ty + i][kk];
#pragma unroll
            for (int j = 0; j < 4; j++) b4[j] = *(const float4*)&Bs[4 * tx + j][kk];
#pragma unroll
            for (int i = 0; i < 4; i++) {
#pragma unroll
                for (int j = 0; j < 4; j++) {
                    acc[i][j] += a4[i].x * b4[j].x;
                    acc[i][j] += a4[i].y * b4[j].y;
                    acc[i][j] += a4[i].z * b4[j].z;
                    acc[i][j] += a4[i].w * b4[j].w;
                }
            }
        }
        __syncthreads();
    }

    float4 bv = *(const float4*)(bias + n0 + 4 * tx);
#pragma unroll
    for (int i = 0; i < 4; i++) {
        float4 o;
        o.x = acc[i][0] + bv.x;
        o.y = acc[i][1] + bv.y;
        o.z = acc[i][2] + bv.z;
        o.w = acc[i][3] + bv.w;
        *(float4*)(h + (size_t)(m0 + 4 * ty + i) * FDIM + n0 + 4 * tx) = o;
    }
}

// ---------------- Kernel 2: sparse aggregate + gate + blend ----------------
// One block (256 threads) per output row (b,i). adj is binary ~5% dense.
__global__ __launch_bounds__(256) void agg_gate(const float* __restrict__ adj,
                                                const float* __restrict__ x,
                                                const float* __restrict__ h,
                                                const float* __restrict__ gw,
                                                const float* __restrict__ gb,
                                                float* __restrict__ out) {
    __shared__ int   lst[NNODE];
    __shared__ int   cnt;
    __shared__ float red[4];
    __shared__ float coeff_s;

    const int t  = threadIdx.x;
    const int bi = blockIdx.x;      // 0..8191
    const int b  = bi >> 9;

    if (t == 0) cnt = 0;
    __syncthreads();

    // Compact nonzero column indices of adj row into LDS.
    const float* arow = adj + (size_t)bi * NNODE;
    float2 av = *(const float2*)(arow + 2 * t);
    if (av.x != 0.0f) { int p = atomicAdd(&cnt, 1); lst[p] = 2 * t; }
    if (av.y != 0.0f) { int p = atomicAdd(&cnt, 1); lst[p] = 2 * t + 1; }
    __syncthreads();

    const int n = cnt;
    const float* hb = h + (size_t)b * NNODE * FDIM;
    float acc = 0.0f;
    for (int p = 0; p < n; p++) {
        int j = lst[p];                       // LDS broadcast (uniform)
        acc += hb[(size_t)j * FDIM + t];      // coalesced row read
    }

    float hp = (acc > 0.0f) ? acc : 0.2f * acc;   // leaky_relu 0.2
    float xv = x[(size_t)bi * FDIM + t];

    // gate: g = x . gw[0:256] + hp . gw[256:512] + gb
    float partial = xv * gw[t] + hp * gw[FDIM + t];
#pragma unroll
    for (int off = 32; off > 0; off >>= 1) partial += __shfl_down(partial, off);
    if ((t & 63) == 0) red[t >> 6] = partial;
    __syncthreads();
    if (t == 0) {
        float g = red[0] + red[1] + red[2] + red[3] + gb[0];
        coeff_s = 1.0f / (1.0f + expf(-g));
    }
    __syncthreads();

    float c = coeff_s;
    out[(size_t)bi * FDIM + t] = c * xv + (1.0f - c) * hp;
}

extern "C" void kernel_launch(void* const* d_in, const int* in_sizes, int n_in,
                              void* d_out, int out_size, void* d_ws, size_t ws_size,
                              hipStream_t stream) {
    const float* x    = (const float*)d_in[0];
    const float* adj  = (const float*)d_in[1];
    const float* W_w  = (const float*)d_in[2];
    const float* W_b  = (const float*)d_in[3];
    // d_in[4] = A  (dead code in reference, unused)
    const float* gw   = (const float*)d_in[5];
    const float* gb   = (const float*)d_in[6];
    float* out = (float*)d_out;
    float* h   = (float*)d_ws;   // 8192*256 f32 = 8 MB scratch

    h_gemm<<<dim3(512), dim3(256), 0, stream>>>(x, W_w, W_b, h);
    agg_gate<<<dim3(M_TOT), dim3(256), 0, stream>>>(adj, x, h, gw, gb, out);
}

// Round 2
// 104.095 us; speedup vs baseline: 1.4188x; 1.4188x over previous
//
#include <hip/hip_runtime.h>
#include <math.h>

// Problem: B=16, N=512, F=256.
// Live computation only (attention matrix is dead code in the reference):
//   h       = x @ W_w^T + W_b                      [B,N,F]   (bf16 MFMA)
//   h_prime = leaky_relu(adj @ h, 0.2)             [B,N,F]   (sparse gather, h bf16)
//   g       = [x, h_prime] @ gate_w^T + gate_b     [B,N,1]
//   out     = sigmoid(g)*x + (1-sigmoid(g))*h_prime

#define BATCH 16
#define NNODE 512
#define FDIM  256
#define M_TOT (BATCH * NNODE)   // 8192

typedef __bf16 bf16x8 __attribute__((ext_vector_type(8)));
typedef float  f32x4  __attribute__((ext_vector_type(4)));

static __device__ __forceinline__ unsigned short f2bf(float f) {
    union { float f; unsigned int i; } v; v.f = f;
    unsigned int r = v.i + 0x7FFFu + ((v.i >> 16) & 1u);   // RNE
    return (unsigned short)(r >> 16);
}
static __device__ __forceinline__ float bf2f(unsigned short u) {
    union { unsigned int i; float f; } v; v.i = ((unsigned int)u) << 16;
    return v.f;
}

// ---------------- Kernel 1: h = x @ W^T + bias  (bf16 MFMA) ----------------
// M=8192, N=256, K=256. BM=128, BN=64, BK=64. 256 threads = 4 waves.
// Wave w computes rows [w*32, w*32+32) as two 16-row tiles x 4 col-tiles.
// LDS row stride 72 bf16 = 36 dwords: dword group-advance 9 (odd) => each
// 8-lane ds_read_b128 phase covers all 8 bank groups => conflict-free.
#define BM 128
#define BN 64
#define BK 64
#define ASTR 72

__global__ __launch_bounds__(256) void h_gemm_mfma(const float* __restrict__ x,
                                                   const float* __restrict__ W,
                                                   const float* __restrict__ bias,
                                                   unsigned short* __restrict__ h) {
    __shared__ unsigned short As[BM * ASTR];   // 18432 B
    __shared__ unsigned short Bs[BN * ASTR];   //  9216 B

    const int t    = threadIdx.x;
    const int wave = t >> 6;
    const int lane = t & 63;
    const int ln   = lane & 15;
    const int quad = lane >> 4;
    const int m0   = (int)(blockIdx.x >> 2) * BM;   // 64 m-tiles
    const int n0   = (int)(blockIdx.x & 3) * BN;    // 4 n-tiles
    const int mA0  = wave * 32;
    const int mA1  = wave * 32 + 16;

    f32x4 acc[2][4] = {};

    for (int k0 = 0; k0 < FDIM; k0 += BK) {
        // Stage A: 128x64 f32 -> bf16. 2048 float4, 8 per thread.
#pragma unroll
        for (int i = 0; i < 8; i++) {
            int fid = i * 256 + t;
            int row = fid >> 4;
            int c4  = (fid & 15) * 4;
            float4 v = *(const float4*)(x + (size_t)(m0 + row) * FDIM + k0 + c4);
            ushort4 bv;
            bv.x = f2bf(v.x); bv.y = f2bf(v.y); bv.z = f2bf(v.z); bv.w = f2bf(v.w);
            *(ushort4*)&As[row * ASTR + c4] = bv;
        }
        // Stage B: W rows n0..n0+63, cols k0..k0+63. 1024 float4, 4 per thread.
#pragma unroll
        for (int i = 0; i < 4; i++) {
            int fid = i * 256 + t;
            int row = fid >> 4;
            int c4  = (fid & 15) * 4;
            float4 v = *(const float4*)(W + (size_t)(n0 + row) * FDIM + k0 + c4);
            ushort4 bv;
            bv.x = f2bf(v.x); bv.y = f2bf(v.y); bv.z = f2bf(v.z); bv.w = f2bf(v.w);
            *(ushort4*)&Bs[row * ASTR + c4] = bv;
        }
        __syncthreads();

#pragma unroll
        for (int ks = 0; ks < BK; ks += 32) {
            const int kb = ks + quad * 8;
            bf16x8 a0 = *(const bf16x8*)&As[(mA0 + ln) * ASTR + kb];
            bf16x8 a1 = *(const bf16x8*)&As[(mA1 + ln) * ASTR + kb];
            bf16x8 b0 = *(const bf16x8*)&Bs[(0  + ln) * ASTR + kb];
            bf16x8 b1 = *(const bf16x8*)&Bs[(16 + ln) * ASTR + kb];
            bf16x8 b2 = *(const bf16x8*)&Bs[(32 + ln) * ASTR + kb];
            bf16x8 b3 = *(const bf16x8*)&Bs[(48 + ln) * ASTR + kb];
            acc[0][0] = __builtin_amdgcn_mfma_f32_16x16x32_bf16(a0, b0, acc[0][0], 0, 0, 0);
            acc[0][1] = __builtin_amdgcn_mfma_f32_16x16x32_bf16(a0, b1, acc[0][1], 0, 0, 0);
            acc[0][2] = __builtin_amdgcn_mfma_f32_16x16x32_bf16(a0, b2, acc[0][2], 0, 0, 0);
            acc[0][3] = __builtin_amdgcn_mfma_f32_16x16x32_bf16(a0, b3, acc[0][3], 0, 0, 0);
            acc[1][0] = __builtin_amdgcn_mfma_f32_16x16x32_bf16(a1, b0, acc[1][0], 0, 0, 0);
            acc[1][1] = __builtin_amdgcn_mfma_f32_16x16x32_bf16(a1, b1, acc[1][1], 0, 0, 0);
            acc[1][2] = __builtin_amdgcn_mfma_f32_16x16x32_bf16(a1, b2, acc[1][2], 0, 0, 0);
            acc[1][3] = __builtin_amdgcn_mfma_f32_16x16x32_bf16(a1, b3, acc[1][3], 0, 0, 0);
        }
        __syncthreads();
    }

    // Epilogue: D[row][col], col = lane&15, row = quad*4 + reg. Add bias, store bf16.
#pragma unroll
    for (int i = 0; i < 2; i++) {
        const int mbase = m0 + (i ? mA1 : mA0) + quad * 4;
#pragma unroll
        for (int j = 0; j < 4; j++) {
            const int gn = n0 + j * 16 + ln;
            const float bv = bias[gn];
            f32x4 c = acc[i][j];
#pragma unroll
            for (int r = 0; r < 4; r++) {
                h[(size_t)(mbase + r) * FDIM + gn] = f2bf(c[r] + bv);
            }
        }
    }
}

// ---------------- Kernel 2: sparse aggregate + gate + blend ----------------
// One block (256 threads) per output row (b,i). adj is binary ~5% dense.
// Neighbor loop unrolled 4x with independent accumulators for MLP latency.
__global__ __launch_bounds__(256) void agg_gate(const float* __restrict__ adj,
                                                const float* __restrict__ x,
                                                const unsigned short* __restrict__ h,
                                                const float* __restrict__ gw,
                                                const float* __restrict__ gb,
                                                float* __restrict__ out) {
    __shared__ int   lst[NNODE];
    __shared__ int   cnt;
    __shared__ float red[4];
    __shared__ float coeff_s;

    const int t  = threadIdx.x;
    const int bi = blockIdx.x;      // 0..8191
    const int b  = bi >> 9;

    if (t == 0) cnt = 0;
    __syncthreads();

    // Compact nonzero column indices of adj row into LDS.
    const float* arow = adj + (size_t)bi * NNODE;
    float2 av = *(const float2*)(arow + 2 * t);
    if (av.x != 0.0f) { int p = atomicAdd(&cnt, 1); lst[p] = 2 * t; }
    if (av.y != 0.0f) { int p = atomicAdd(&cnt, 1); lst[p] = 2 * t + 1; }

    const float xv = x[(size_t)bi * FDIM + t];   // overlap with compaction
    __syncthreads();

    const int n = cnt;
    const unsigned short* hb = h + (size_t)b * NNODE * FDIM;
    float a0 = 0.0f, a1 = 0.0f, a2 = 0.0f, a3 = 0.0f;
    int p = 0;
    for (; p + 4 <= n; p += 4) {
        int j0 = lst[p], j1 = lst[p + 1], j2 = lst[p + 2], j3 = lst[p + 3];
        unsigned short v0 = hb[(size_t)j0 * FDIM + t];
        unsigned short v1 = hb[(size_t)j1 * FDIM + t];
        unsigned short v2 = hb[(size_t)j2 * FDIM + t];
        unsigned short v3 = hb[(size_t)j3 * FDIM + t];
        a0 += bf2f(v0); a1 += bf2f(v1); a2 += bf2f(v2); a3 += bf2f(v3);
    }
    for (; p < n; p++) a0 += bf2f(hb[(size_t)lst[p] * FDIM + t]);
    float acc = (a0 + a1) + (a2 + a3);

    float hp = (acc > 0.0f) ? acc : 0.2f * acc;   // leaky_relu 0.2

    // gate: g = x . gw[0:256] + hp . gw[256:512] + gb
    float partial = xv * gw[t] + hp * gw[FDIM + t];
#pragma unroll
    for (int off = 32; off > 0; off >>= 1) partial += __shfl_down(partial, off);
    if ((t & 63) == 0) red[t >> 6] = partial;
    __syncthreads();
    if (t == 0) {
        float g = red[0] + red[1] + red[2] + red[3] + gb[0];
        coeff_s = 1.0f / (1.0f + expf(-g));
    }
    __syncthreads();

    float c = coeff_s;
    out[(size_t)bi * FDIM + t] = c * xv + (1.0f - c) * hp;
}

extern "C" void kernel_launch(void* const* d_in, const int* in_sizes, int n_in,
                              void* d_out, int out_size, void* d_ws, size_t ws_size,
                              hipStream_t stream) {
    const float* x    = (const float*)d_in[0];
    const float* adj  = (const float*)d_in[1];
    const float* W_w  = (const float*)d_in[2];
    const float* W_b  = (const float*)d_in[3];
    // d_in[4] = A  (dead code in reference, unused)
    const float* gw   = (const float*)d_in[5];
    const float* gb   = (const float*)d_in[6];
    float* out = (float*)d_out;
    unsigned short* h = (unsigned short*)d_ws;   // 8192*256 bf16 = 4 MB scratch

    h_gemm_mfma<<<dim3(256), dim3(256), 0, stream>>>(x, W_w, W_b, h);
    agg_gate<<<dim3(M_TOT), dim3(256), 0, stream>>>(adj, x, h, gw, gb, out);
}